// Round 6
// baseline (339.225 us; speedup 1.0000x reference)
//
#include <hip/hip_runtime.h>
#include <stdint.h>

#define BB 4
#define SDIM 128
#define S2 (SDIM*SDIM)          // 16384
#define S3 ((size_t)SDIM*S2)    // 2097152

// Per-wave probe: detect bool storage width (1B vs 4B) from structure
// (valid is a prefix of >=64 trues; element S-1 is always false), then
// return len[b] = popcount of the valid prefix. All 64 lanes participate.
__device__ __forceinline__ int probe_len(const void* em, int b, int lane) {
    const unsigned char* p8 = (const unsigned char*)em;
    const int* p32 = (const int*)em;
    const int t0 = lane, t1 = lane + 64;
    const size_t i0 = (size_t)b*S2 + (size_t)t0*SDIM + t0;
    const size_t i1 = (size_t)b*S2 + (size_t)t1*SDIM + t1;
    const unsigned char a0 = p8[i0], a1 = p8[i1];
    const bool ok = (a0 != 0) && (t1 != SDIM-1 || a1 == 0);
    const unsigned long long mok = __ballot(ok);
    const bool use8 = (mok == ~0ull);   // wave-uniform
    int v0, v1;
    if (use8) { v0 = (a0 != 0); v1 = (a1 != 0); }
    else      { v0 = (p32[i0] != 0); v1 = (p32[i1] != 0); }
    return __popcll(__ballot(v0)) + __popcll(__ballot(v1));
}

__device__ __forceinline__ float sigf(float x) { return 1.f / (1.f + expf(-x)); }

// Fire-and-forget global->LDS copy: 64 lanes x 16B = 1KB (2 rows of 512B).
__device__ __forceinline__ void gll16(const float* g, float* l) {
    __builtin_amdgcn_global_load_lds(
        (const __attribute__((address_space(1))) void*)g,
        (__attribute__((address_space(3))) void*)l, 16, 0, 0);
}

// Streaming k_prep: block (b,i). Init q/pe/ps/peT one-shot, then stream the
// s_split rows j=i..len-1 through a double-buffered LDS pipeline with counted
// vmcnt (1 gll/wave/chunk in flight ahead). splitsum is now a single buffer.
__global__ __launch_bounds__(256) void k_prep(
    const float* __restrict__ s_edge, const float* __restrict__ s_const,
    const float* __restrict__ s_split, const void* __restrict__ em,
    float* __restrict__ q_edge, float* __restrict__ q_span,
    float* __restrict__ splitsum,
    float* __restrict__ peA, float* __restrict__ peB,
    float* __restrict__ peTA, float* __restrict__ peTB,
    float* __restrict__ psA, float* __restrict__ psB) {
    __shared__ float pbuf[2][8][SDIM];   // 8 KB
    __shared__ float pred[2][SDIM];      // 1 KB
    const int b = blockIdx.x >> 7, i = blockIdx.x & 127;
    const int tid = threadIdx.x, lane = tid & 63, wave = tid >> 6, half = lane >> 5;
    const int len = probe_len(em, b, lane);
    const int lm1 = len - 1;
    const size_t vb = (size_t)b*S2;
    if (tid < SDIM) {
        const size_t ro = vb + (size_t)i*SDIM + tid;
        const float qe = s_edge[ro];
        const float qs = (i <= tid) ? s_const[ro] : s_const[vb + (size_t)tid*SDIM + i];
        q_edge[ro] = qe;
        q_span[ro] = qs;
        const float se = sigf(qe), ss = sigf(qs);
        peA[ro] = se; peB[ro] = se;
        psA[ro] = ss; psB[ro] = ss;
        const size_t to = vb + (size_t)tid*SDIM + i;
        peTA[to] = se; peTB[to] = se;
    }
    float sumv = 0.f;
    if (i >= 1 && i < len) {
        const float* sb = s_split + (size_t)b*S3 + (size_t)i*S2;
        const int sq = (lane & 31) * 4;
        const int nc = (len - i + 7) >> 3;   // chunks of 8 rows, j = i+8c+r
        #define PSTAGE(CB, C) { \
            const int jc_ = min(i + 8*(C) + 2*wave + half, lm1); \
            gll16(sb + (size_t)jc_*SDIM + sq, &pbuf[CB][2*wave][0]); }
        PSTAGE(0, 0)
        const int k = tid & 127, rh = tid >> 7;
        float acc = 0.f;
        for (int c = 0; c < nc; ++c) {
            const int cb = c & 1;
            if (c + 1 < nc) {
                PSTAGE(cb ^ 1, c + 1)
                asm volatile("s_waitcnt vmcnt(1)" ::: "memory");
            } else {
                asm volatile("s_waitcnt vmcnt(0)" ::: "memory");
            }
            __builtin_amdgcn_s_barrier();
            #pragma unroll
            for (int rr2 = 0; rr2 < 4; ++rr2) {
                const int r = rh*4 + rr2;
                const int j = i + 8*c + r;
                const float v = pbuf[cb][r][k];
                acc += (j < len && j != k) ? v : 0.f;
            }
            __builtin_amdgcn_s_barrier();
        }
        #undef PSTAGE
        pred[rh][k] = acc;
        __syncthreads();
        if (tid >= 1 && tid < len && tid < SDIM)
            sumv = pred[0][tid] + pred[1][tid];
    }
    if (tid < SDIM) splitsum[vb + (size_t)i*SDIM + tid] = sumv;
}

// Streaming k_upd, v7: ONE block per output row (grid 1024, 1D).
//   gid&1==0: edge row h (all 128 m);  gid&1==1: span row i (all 128 j).
// Double-buffered LDS chunks of 8 rows; per chunk each wave issues its gll
// for the NEXT chunk, then s_waitcnt vmcnt(6|3) (counted — previous chunk
// complete, next still in flight), raw s_barrier, compute, s_barrier.
// Fixed costs (probe, setup, drain ramp) paid once per ~10us block instead
// of once per 3.6us block (rounds 0-5's disease). Sigmoid ping-pong epilogue
// unchanged; math identical to the passing round-5 kernel.
__global__ __launch_bounds__(256) void k_upd(
    const float* __restrict__ s_sib, const float* __restrict__ s_cop,
    const float* __restrict__ s_grd, const float* __restrict__ s_ep,
    const float* __restrict__ s_hb,  const float* __restrict__ s_he,
    const float* __restrict__ peA, const float* __restrict__ peTA,
    const float* __restrict__ psA, const float* __restrict__ splitsum,
    const void* __restrict__ em,
    float* __restrict__ q_edge, float* __restrict__ q_span,
    float* __restrict__ peB, float* __restrict__ peTB, float* __restrict__ psB) {
    __shared__ float buf[2][6][8][SDIM];   // 48 KB
    __shared__ float sml[3*SDIM];          // 1.5 KB
    const int gid = blockIdx.x;
    const int part = gid & 1, b = (gid >> 1) & 3, row = gid >> 3;
    const int tid = threadIdx.x, wave = tid >> 6, lane = tid & 63;
    const int half = lane >> 5, sq = (lane & 31) * 4;
    const int len = probe_len(em, b, lane);
    const int lm1 = len - 1;
    const size_t vb = (size_t)b*S2;

    if (part == 0) {
        const int h = row;
        if (h >= len) return;
        const size_t tb = (size_t)b*S3 + (size_t)h*S2;
        const size_t hrow = vb + (size_t)h*SDIM;
        const float4 pe4 = *(const float4*)(peA + hrow + sq);
        if (tid < SDIM) sml[tid] = q_edge[hrow + tid];
        __syncthreads();                     // drains init loads; pipeline clean
        const int nc = (len + 7) >> 3;
        #define ESTAGE(CB, C) { \
            const int mc_ = min(8*(C) + 2*wave + half, lm1); \
            const size_t go = (size_t)mc_*SDIM + sq; \
            gll16(s_sib + tb + go, &buf[CB][0][2*wave][0]); \
            gll16(s_cop + tb + go, &buf[CB][1][2*wave][0]); \
            gll16(s_grd + tb + go, &buf[CB][2][2*wave][0]); \
            gll16(s_ep  + tb + go, &buf[CB][3][2*wave][0]); \
            gll16(peTA + vb + go, &buf[CB][4][2*wave][0]); \
            gll16(psA  + vb + go, &buf[CB][5][2*wave][0]); }
        ESTAGE(0, 0)
        for (int c = 0; c < nc; ++c) {
            const int cb = c & 1;
            if (c + 1 < nc) {
                ESTAGE(cb ^ 1, c + 1)
                asm volatile("s_waitcnt vmcnt(6)" ::: "memory");
            } else {
                asm volatile("s_waitcnt vmcnt(0)" ::: "memory");
            }
            __builtin_amdgcn_s_barrier();
            const int r = 2*wave + half;
            const int m = 8*c + r;
            const bool mv = (m < len);
            const float4 sibv = *(const float4*)&buf[cb][0][r][sq];
            const float4 copv = *(const float4*)&buf[cb][1][r][sq];
            const float4 grdv = *(const float4*)&buf[cb][2][r][sq];
            const float4 epvv = *(const float4*)&buf[cb][3][r][sq];
            const float4 petv = *(const float4*)&buf[cb][4][r][sq];
            const float4 psvv = *(const float4*)&buf[cb][5][r][sq];
            float rr = 0.f;
            #define TERM(C, F) { const int s = sq + C;                               \
                const bool bs = mv && (s < len) && (m != s);                         \
                const float fem = (bs && (h != s)) ? 1.f : 0.f;                      \
                const float fnc = (bs && ((m >= h && s >= h) || (m <= h && s <= h))) \
                                  ? 1.f : 0.f;                                       \
                rr += fem * (sibv.F*pe4.F + copv.F*petv.F + grdv.F*psvv.F)           \
                    + fnc * (epvv.F*psvv.F); }
            TERM(0, x) TERM(1, y) TERM(2, z) TERM(3, w)
            #undef TERM
            rr += __shfl_xor(rr, 16); rr += __shfl_xor(rr, 8); rr += __shfl_xor(rr, 4);
            rr += __shfl_xor(rr, 2);  rr += __shfl_xor(rr, 1);
            if ((lane & 31) == 0 && mv) {
                const float qn = sml[m] + rr;
                q_edge[hrow + m] = qn;
                const float sg = sigf(qn);
                peB[hrow + m] = sg;
                peTB[vb + (size_t)m*SDIM + h] = sg;
            }
            __builtin_amdgcn_s_barrier();
        }
        #undef ESTAGE
    } else {
        const int i = row;
        if (i < 1 || i >= len) return;
        const size_t irow = vb + (size_t)i*SDIM;
        const size_t ibase = (size_t)b*S3 + (size_t)i*S2;
        const float4 peTi4 = *(const float4*)(peTA + irow + sq);
        for (int u = tid; u < 3*SDIM; u += 256) {   // stage per-row scalars
            const int surf = u >> 7, t2 = u & 127;
            sml[u] = (surf == 0) ? q_span[irow + t2]
                   : (surf == 1) ? psA[irow + t2] : splitsum[irow + t2];
        }
        __syncthreads();
        // Chunks entirely j<=i: scalar-only writes (rr would be 0 there).
        const int c0 = (i + 1) >> 3;
        const int nc = (len + 7) >> 3;
        for (int j2 = tid; j2 < 8*c0; j2 += 256) {
            if (j2 >= 1) {
                const float qn = sml[j2] + sml[SDIM + j2] * sml[2*SDIM + j2];
                q_span[irow + j2] = qn;
                psB[irow + j2] = sigf(qn);
            }
        }
        if (c0 < nc) {
            #define SSTAGE(CB, C) { \
                const int jc_ = min(8*(C) + 2*wave + half, lm1); \
                gll16(s_hb + ibase + (size_t)jc_*SDIM + sq, &buf[CB][0][2*wave][0]); \
                gll16(s_he + (size_t)b*S3 + (size_t)jc_*S2 + (size_t)i*SDIM + sq, \
                      &buf[CB][1][2*wave][0]); \
                gll16(peTA + vb + (size_t)jc_*SDIM + sq, &buf[CB][2][2*wave][0]); }
            SSTAGE(0, c0)
            for (int c = c0; c < nc; ++c) {
                const int cb = (c - c0) & 1;
                if (c + 1 < nc) {
                    SSTAGE(cb ^ 1, c + 1)
                    asm volatile("s_waitcnt vmcnt(3)" ::: "memory");
                } else {
                    asm volatile("s_waitcnt vmcnt(0)" ::: "memory");
                }
                __builtin_amdgcn_s_barrier();
                const int r = 2*wave + half;
                const int j = 8*c + r;
                const bool act = (j > i) && (j < len);
                const float4 hbv  = *(const float4*)&buf[cb][0][r][sq];
                const float4 hev  = *(const float4*)&buf[cb][1][r][sq];
                const float4 ptjv = *(const float4*)&buf[cb][2][r][sq];
                float rr = 0.f;
                #define TERM(C, F) { const int s = sq + C;                           \
                    const float f = (act && s >= 1 && s < len && (s < i || s > j))   \
                                    ? 1.f : 0.f;                                     \
                    rr += f * (hbv.F*peTi4.F + hev.F*ptjv.F); }
                TERM(0, x) TERM(1, y) TERM(2, z) TERM(3, w)
                #undef TERM
                rr += __shfl_xor(rr, 16); rr += __shfl_xor(rr, 8); rr += __shfl_xor(rr, 4);
                rr += __shfl_xor(rr, 2);  rr += __shfl_xor(rr, 1);
                if ((lane & 31) == 0 && j >= 1 && j < len) {
                    const float qn = sml[j] + rr + sml[SDIM + j] * sml[2*SDIM + j];
                    q_span[irow + j] = qn;
                    psB[irow + j] = sigf(qn);
                }
                __builtin_amdgcn_s_barrier();
            }
            #undef SSTAGE
        }
    }
}

extern "C" void kernel_launch(void* const* d_in, const int* in_sizes, int n_in,
                              void* d_out, int out_size, void* d_ws, size_t ws_size,
                              hipStream_t stream) {
    const float* s_edge  = (const float*)d_in[0];
    const float* s_const = (const float*)d_in[1];
    const float* s_sib   = (const float*)d_in[2];
    const float* s_cop   = (const float*)d_in[3];
    const float* s_grd   = (const float*)d_in[4];
    const float* s_ep    = (const float*)d_in[5];
    const float* s_split = (const float*)d_in[6];
    const float* s_hb    = (const float*)d_in[7];
    const float* s_he    = (const float*)d_in[8];
    const void*  em      = d_in[9];
    (void)in_sizes; (void)n_in; (void)out_size; (void)ws_size;

    float* q_edge = (float*)d_out;
    float* q_span = q_edge + (size_t)BB * S2;

    char* ws = (char*)d_ws;
    const size_t SZ = (size_t)BB * S2 * sizeof(float);   // 256 KiB
    float* splitsum = (float*)(ws);
    float* peA    = (float*)(ws + 1*SZ);
    float* peTA   = (float*)(ws + 2*SZ);
    float* psA    = (float*)(ws + 3*SZ);
    float* peB    = (float*)(ws + 4*SZ);
    float* peTB   = (float*)(ws + 5*SZ);
    float* psB    = (float*)(ws + 6*SZ);

    const int NB = BB * SDIM;  // 512
    hipLaunchKernelGGL(k_prep, dim3(NB), dim3(256), 0, stream,
                       s_edge, s_const, s_split, em, q_edge, q_span,
                       splitsum, peA, peB, peTA, peTB, psA, psB);
    for (int it = 0; it < 3; ++it) {
        const int s = it & 1;
        const float* peR  = s ? peB  : peA;
        const float* peTR = s ? peTB : peTA;
        const float* psR  = s ? psB  : psA;
        float* peW  = s ? peA  : peB;
        float* peTW = s ? peTA : peTB;
        float* psW  = s ? psA  : psB;
        hipLaunchKernelGGL(k_upd, dim3(2*NB), dim3(256), 0, stream,
                           s_sib, s_cop, s_grd, s_ep, s_hb, s_he,
                           peR, peTR, psR, splitsum, em,
                           q_edge, q_span, peW, peTW, psW);
    }
}

// Round 7
// 289.533 us; speedup vs baseline: 1.1716x; 1.1716x over previous
//
#include <hip/hip_runtime.h>
#include <stdint.h>

#define BB 4
#define SDIM 128
#define S2 (SDIM*SDIM)          // 16384
#define S3 ((size_t)SDIM*S2)    // 2097152

typedef float vf4 __attribute__((ext_vector_type(4)));

// Per-wave probe: detect bool storage width (1B vs 4B) from structure
// (valid is a prefix of >=64 trues; element S-1 is always false), then
// return len[b] = popcount of the valid prefix. All 64 lanes participate.
__device__ __forceinline__ int probe_len(const void* em, int b, int lane) {
    const unsigned char* p8 = (const unsigned char*)em;
    const int* p32 = (const int*)em;
    const int t0 = lane, t1 = lane + 64;
    const size_t i0 = (size_t)b*S2 + (size_t)t0*SDIM + t0;
    const size_t i1 = (size_t)b*S2 + (size_t)t1*SDIM + t1;
    const unsigned char a0 = p8[i0], a1 = p8[i1];
    const bool ok = (a0 != 0) && (t1 != SDIM-1 || a1 == 0);
    const unsigned long long mok = __ballot(ok);
    const bool use8 = (mok == ~0ull);   // wave-uniform
    int v0, v1;
    if (use8) { v0 = (a0 != 0); v1 = (a1 != 0); }
    else      { v0 = (p32[i0] != 0); v1 = (p32[i1] != 0); }
    return __popcll(__ballot(v0)) + __popcll(__ballot(v1));
}

__device__ __forceinline__ float sigf(float x) { return 1.f / (1.f + expf(-x)); }

// Fused: q init + pe/peT/ps init (both ping-pong buffers) + splitsum partials.
// Grid (B*S, 2). The 8 strip loads are issued INSIDE one asm block: the
// compiler cannot split/serialize them -> one batched latency wait.
__global__ __launch_bounds__(256) void k_prep(
    const float* __restrict__ s_edge, const float* __restrict__ s_const,
    const float* __restrict__ s_split, const void* __restrict__ em,
    float* __restrict__ q_edge, float* __restrict__ q_span,
    float* __restrict__ split0, float* __restrict__ split1,
    float* __restrict__ peA, float* __restrict__ peB,
    float* __restrict__ peTA, float* __restrict__ peTB,
    float* __restrict__ psA, float* __restrict__ psB) {
    const int b = blockIdx.x >> 7, i = blockIdx.x & 127;
    const int y = blockIdx.y;
    const int tid = threadIdx.x, lane = tid & 63;
    const int len = probe_len(em, b, lane);
    const int lm1 = len - 1;
    const size_t vb = (size_t)b*S2;
    if (y == 0 && tid < SDIM) {
        const size_t ro = vb + (size_t)i*SDIM + tid;
        const float qe = s_edge[ro];
        const float qs = (i <= tid) ? s_const[ro] : s_const[vb + (size_t)tid*SDIM + i];
        q_edge[ro] = qe;
        q_span[ro] = qs;
        const float se = sigf(qe), ss = sigf(qs);
        peA[ro] = se; peB[ro] = se;
        psA[ro] = ss; psB[ro] = ss;
        const size_t to = vb + (size_t)tid*SDIM + i;
        peTA[to] = se; peTB[to] = se;
    }
    const int g = tid >> 5;            // j-group 0..7
    const int kq = (tid & 31) * 4;     // k base
    vf4 acc = (vf4)0.f;
    if (i >= 1 && i < len && kq < len) {
        const float* base = s_split + (size_t)b*S3 + (size_t)i*S2;
        const int j0 = i + g + 8*y;    // then stride 16; 8 steps cover j-i < 128
        int jv[8];
        const float* pa[8];
        #pragma unroll
        for (int t = 0; t < 8; ++t) {
            const int j = j0 + 16*t;
            jv[t] = j;
            pa[t] = base + (size_t)min(j, lm1)*SDIM + kq;
        }
        vf4 v[8];
        asm volatile(
            "global_load_dwordx4 %0, %8, off\n\t"
            "global_load_dwordx4 %1, %9, off\n\t"
            "global_load_dwordx4 %2, %10, off\n\t"
            "global_load_dwordx4 %3, %11, off\n\t"
            "global_load_dwordx4 %4, %12, off\n\t"
            "global_load_dwordx4 %5, %13, off\n\t"
            "global_load_dwordx4 %6, %14, off\n\t"
            "global_load_dwordx4 %7, %15, off\n\t"
            "s_waitcnt vmcnt(0)"
            : "=&v"(v[0]), "=&v"(v[1]), "=&v"(v[2]), "=&v"(v[3]),
              "=&v"(v[4]), "=&v"(v[5]), "=&v"(v[6]), "=&v"(v[7])
            : "v"(pa[0]), "v"(pa[1]), "v"(pa[2]), "v"(pa[3]),
              "v"(pa[4]), "v"(pa[5]), "v"(pa[6]), "v"(pa[7]));
        #pragma unroll
        for (int t = 0; t < 8; ++t) {
            const int j = jv[t];
            const bool jb = (j < len);
            acc.x += (jb && j != kq+0) ? v[t].x : 0.f;
            acc.y += (jb && j != kq+1) ? v[t].y : 0.f;
            acc.z += (jb && j != kq+2) ? v[t].z : 0.f;
            acc.w += (jb && j != kq+3) ? v[t].w : 0.f;
        }
    }
    __shared__ float red[8][SDIM];
    *(vf4*)&red[g][kq] = acc;
    __syncthreads();
    if (tid < SDIM) {
        float s = 0.f;
        #pragma unroll
        for (int gg = 0; gg < 8; ++gg) s += red[gg][tid];
        float* out = y ? split1 : split0;
        out[vb + (size_t)i*SDIM + tid] = (tid >= 1 && tid < len) ? s : 0.f;
    }
}

// Fused per-iteration update, v8: r2's exact geometry/math (4096 blocks,
// y<4 edge m-chunk / y>=4 span j-chunk, shuffle-reduce, ping-pong sigmoid
// epilogue), with the load phase replaced by ONE asm volatile block holding
// all 29 loads + final s_waitcnt vmcnt(0). The compiler cannot re-serialize
// loads it does not emit: 29 loads issue back-to-back, exactly one latency
// wait per phase. VGPR ~180-220 expected (earlyclobber outputs + addresses).
__global__ __launch_bounds__(256) void k_upd(
    const float* __restrict__ s_sib, const float* __restrict__ s_cop,
    const float* __restrict__ s_grd, const float* __restrict__ s_ep,
    const float* __restrict__ s_hb,  const float* __restrict__ s_he,
    const float* __restrict__ peA, const float* __restrict__ peTA,
    const float* __restrict__ psA,
    const float* __restrict__ split0, const float* __restrict__ split1,
    const void* __restrict__ em,
    float* __restrict__ q_edge, float* __restrict__ q_span,
    float* __restrict__ peB, float* __restrict__ peTB, float* __restrict__ psB) {
    const int b = blockIdx.x >> 7, row = blockIdx.x & 127;
    const int tid = threadIdx.x, wave = tid >> 6, lane = tid & 63;
    const int half = lane >> 5, sq = (lane & 31) * 4;
    const int len = probe_len(em, b, lane);
    const int lm1 = len - 1;
    const int sqa = min(sq, lm1 & ~3);     // clamped column base (address only)
    const size_t vb = (size_t)b*S2;

    if (blockIdx.y < 4) {
        const int h = row;
        if (h >= len) return;
        const int m0 = blockIdx.y * 32;
        if (m0 >= len) return;
        const size_t tb = (size_t)b*S3 + (size_t)h*S2;
        const size_t hrow = vb + (size_t)h*SDIM;
        int mr[4];
        const float* pa[29];
        #pragma unroll
        for (int it = 0; it < 4; ++it) {
            const int m = m0 + 8*it + 2*wave + half;
            mr[it] = m;
            const int mc = min(m, lm1);    // clamped row (address only)
            const size_t ro = tb + (size_t)mc*SDIM + sqa;
            const size_t vo = vb + (size_t)mc*SDIM + sqa;
            pa[0  + it] = s_sib + ro;
            pa[4  + it] = s_cop + ro;
            pa[8  + it] = s_grd + ro;
            pa[12 + it] = s_ep  + ro;
            pa[16 + it] = peTA + vo;
            pa[20 + it] = psA  + vo;
            pa[25 + it] = q_edge + hrow + mc;
        }
        pa[24] = peA + hrow + sqa;
        vf4 o[25]; float qo[4];
        asm volatile(
            "global_load_dwordx4 %0, %29, off\n\t"
            "global_load_dwordx4 %1, %30, off\n\t"
            "global_load_dwordx4 %2, %31, off\n\t"
            "global_load_dwordx4 %3, %32, off\n\t"
            "global_load_dwordx4 %4, %33, off\n\t"
            "global_load_dwordx4 %5, %34, off\n\t"
            "global_load_dwordx4 %6, %35, off\n\t"
            "global_load_dwordx4 %7, %36, off\n\t"
            "global_load_dwordx4 %8, %37, off\n\t"
            "global_load_dwordx4 %9, %38, off\n\t"
            "global_load_dwordx4 %10, %39, off\n\t"
            "global_load_dwordx4 %11, %40, off\n\t"
            "global_load_dwordx4 %12, %41, off\n\t"
            "global_load_dwordx4 %13, %42, off\n\t"
            "global_load_dwordx4 %14, %43, off\n\t"
            "global_load_dwordx4 %15, %44, off\n\t"
            "global_load_dwordx4 %16, %45, off\n\t"
            "global_load_dwordx4 %17, %46, off\n\t"
            "global_load_dwordx4 %18, %47, off\n\t"
            "global_load_dwordx4 %19, %48, off\n\t"
            "global_load_dwordx4 %20, %49, off\n\t"
            "global_load_dwordx4 %21, %50, off\n\t"
            "global_load_dwordx4 %22, %51, off\n\t"
            "global_load_dwordx4 %23, %52, off\n\t"
            "global_load_dwordx4 %24, %53, off\n\t"
            "global_load_dword %25, %54, off\n\t"
            "global_load_dword %26, %55, off\n\t"
            "global_load_dword %27, %56, off\n\t"
            "global_load_dword %28, %57, off\n\t"
            "s_waitcnt vmcnt(0)"
            : "=&v"(o[0]),  "=&v"(o[1]),  "=&v"(o[2]),  "=&v"(o[3]),
              "=&v"(o[4]),  "=&v"(o[5]),  "=&v"(o[6]),  "=&v"(o[7]),
              "=&v"(o[8]),  "=&v"(o[9]),  "=&v"(o[10]), "=&v"(o[11]),
              "=&v"(o[12]), "=&v"(o[13]), "=&v"(o[14]), "=&v"(o[15]),
              "=&v"(o[16]), "=&v"(o[17]), "=&v"(o[18]), "=&v"(o[19]),
              "=&v"(o[20]), "=&v"(o[21]), "=&v"(o[22]), "=&v"(o[23]),
              "=&v"(o[24]),
              "=&v"(qo[0]), "=&v"(qo[1]), "=&v"(qo[2]), "=&v"(qo[3])
            : "v"(pa[0]),  "v"(pa[1]),  "v"(pa[2]),  "v"(pa[3]),
              "v"(pa[4]),  "v"(pa[5]),  "v"(pa[6]),  "v"(pa[7]),
              "v"(pa[8]),  "v"(pa[9]),  "v"(pa[10]), "v"(pa[11]),
              "v"(pa[12]), "v"(pa[13]), "v"(pa[14]), "v"(pa[15]),
              "v"(pa[16]), "v"(pa[17]), "v"(pa[18]), "v"(pa[19]),
              "v"(pa[20]), "v"(pa[21]), "v"(pa[22]), "v"(pa[23]),
              "v"(pa[24]), "v"(pa[25]), "v"(pa[26]), "v"(pa[27]),
              "v"(pa[28]));
        const vf4 pe4 = o[24];
        #pragma unroll
        for (int it = 0; it < 4; ++it) {
            const int m = mr[it];
            const bool mv = (m < len);
            float r = 0.f;
            #define TERM(C, F) { const int s = sq + C;                               \
                const bool bs = mv && (s < len) && (m != s);                         \
                const float fem = (bs && (h != s)) ? 1.f : 0.f;                      \
                const float fnc = (bs && ((m >= h && s >= h) || (m <= h && s <= h))) \
                                  ? 1.f : 0.f;                                       \
                r += fem * (o[0+it].F*pe4.F + o[4+it].F*o[16+it].F + o[8+it].F*o[20+it].F) \
                   + fnc * (o[12+it].F*o[20+it].F); }
            TERM(0, x) TERM(1, y) TERM(2, z) TERM(3, w)
            #undef TERM
            r += __shfl_xor(r, 16); r += __shfl_xor(r, 8); r += __shfl_xor(r, 4);
            r += __shfl_xor(r, 2);  r += __shfl_xor(r, 1);
            if ((lane & 31) == 0 && mv) {
                const float qn = qo[it] + r;
                q_edge[hrow + m] = qn;
                const float sg = sigf(qn);
                peB[hrow + m] = sg;
                peTB[vb + (size_t)m*SDIM + h] = sg;
            }
        }
    } else {
        const int i = row;
        if (i < 1 || i >= len) return;
        const int j0 = (blockIdx.y - 4) * 32;
        if (j0 >= len) return;
        const size_t irow = vb + (size_t)i*SDIM;
        int jr[4];
        const float* pa[29];
        #pragma unroll
        for (int it = 0; it < 4; ++it) {
            const int j = j0 + 8*it + 2*wave + half;
            jr[it] = j;
            const int jc = min(j, lm1);    // clamped row (address only)
            pa[0 + it] = s_hb + (size_t)b*S3 + (size_t)i*S2 + (size_t)jc*SDIM + sqa;
            pa[4 + it] = s_he + (size_t)b*S3 + (size_t)jc*S2 + (size_t)i*SDIM + sqa;
            pa[8 + it] = peTA + vb + (size_t)jc*SDIM + sqa;
            pa[13 + it] = q_span + irow + jc;
            pa[17 + it] = psA + irow + jc;
            pa[21 + it] = split0 + irow + jc;
            pa[25 + it] = split1 + irow + jc;
        }
        pa[12] = peTA + irow + sqa;
        vf4 o[13]; float sc[16];
        asm volatile(
            "global_load_dwordx4 %0, %29, off\n\t"
            "global_load_dwordx4 %1, %30, off\n\t"
            "global_load_dwordx4 %2, %31, off\n\t"
            "global_load_dwordx4 %3, %32, off\n\t"
            "global_load_dwordx4 %4, %33, off\n\t"
            "global_load_dwordx4 %5, %34, off\n\t"
            "global_load_dwordx4 %6, %35, off\n\t"
            "global_load_dwordx4 %7, %36, off\n\t"
            "global_load_dwordx4 %8, %37, off\n\t"
            "global_load_dwordx4 %9, %38, off\n\t"
            "global_load_dwordx4 %10, %39, off\n\t"
            "global_load_dwordx4 %11, %40, off\n\t"
            "global_load_dwordx4 %12, %41, off\n\t"
            "global_load_dword %13, %42, off\n\t"
            "global_load_dword %14, %43, off\n\t"
            "global_load_dword %15, %44, off\n\t"
            "global_load_dword %16, %45, off\n\t"
            "global_load_dword %17, %46, off\n\t"
            "global_load_dword %18, %47, off\n\t"
            "global_load_dword %19, %48, off\n\t"
            "global_load_dword %20, %49, off\n\t"
            "global_load_dword %21, %50, off\n\t"
            "global_load_dword %22, %51, off\n\t"
            "global_load_dword %23, %52, off\n\t"
            "global_load_dword %24, %53, off\n\t"
            "global_load_dword %25, %54, off\n\t"
            "global_load_dword %26, %55, off\n\t"
            "global_load_dword %27, %56, off\n\t"
            "global_load_dword %28, %57, off\n\t"
            "s_waitcnt vmcnt(0)"
            : "=&v"(o[0]),  "=&v"(o[1]),  "=&v"(o[2]),  "=&v"(o[3]),
              "=&v"(o[4]),  "=&v"(o[5]),  "=&v"(o[6]),  "=&v"(o[7]),
              "=&v"(o[8]),  "=&v"(o[9]),  "=&v"(o[10]), "=&v"(o[11]),
              "=&v"(o[12]),
              "=&v"(sc[0]),  "=&v"(sc[1]),  "=&v"(sc[2]),  "=&v"(sc[3]),
              "=&v"(sc[4]),  "=&v"(sc[5]),  "=&v"(sc[6]),  "=&v"(sc[7]),
              "=&v"(sc[8]),  "=&v"(sc[9]),  "=&v"(sc[10]), "=&v"(sc[11]),
              "=&v"(sc[12]), "=&v"(sc[13]), "=&v"(sc[14]), "=&v"(sc[15])
            : "v"(pa[0]),  "v"(pa[1]),  "v"(pa[2]),  "v"(pa[3]),
              "v"(pa[4]),  "v"(pa[5]),  "v"(pa[6]),  "v"(pa[7]),
              "v"(pa[8]),  "v"(pa[9]),  "v"(pa[10]), "v"(pa[11]),
              "v"(pa[12]), "v"(pa[13]), "v"(pa[14]), "v"(pa[15]),
              "v"(pa[16]), "v"(pa[17]), "v"(pa[18]), "v"(pa[19]),
              "v"(pa[20]), "v"(pa[21]), "v"(pa[22]), "v"(pa[23]),
              "v"(pa[24]), "v"(pa[25]), "v"(pa[26]), "v"(pa[27]),
              "v"(pa[28]));
        const vf4 peTi4 = o[12];
        #pragma unroll
        for (int it = 0; it < 4; ++it) {
            const int j = jr[it];
            const bool act = (j > i) && (j < len);
            float r = 0.f;
            #define TERM(C, F) { const int s = sq + C;                               \
                const float f = (act && s >= 1 && s < len && (s < i || s > j))       \
                                ? 1.f : 0.f;                                         \
                r += f * (o[0+it].F*peTi4.F + o[4+it].F*o[8+it].F); }
            TERM(0, x) TERM(1, y) TERM(2, z) TERM(3, w)
            #undef TERM
            r += __shfl_xor(r, 16); r += __shfl_xor(r, 8); r += __shfl_xor(r, 4);
            r += __shfl_xor(r, 2);  r += __shfl_xor(r, 1);
            if ((lane & 31) == 0 && j >= 1 && j < len) {
                const float qn = sc[0+it] + r + sc[4+it] * (sc[8+it] + sc[12+it]);
                q_span[irow + j] = qn;
                psB[irow + j] = sigf(qn);
            }
        }
    }
}

extern "C" void kernel_launch(void* const* d_in, const int* in_sizes, int n_in,
                              void* d_out, int out_size, void* d_ws, size_t ws_size,
                              hipStream_t stream) {
    const float* s_edge  = (const float*)d_in[0];
    const float* s_const = (const float*)d_in[1];
    const float* s_sib   = (const float*)d_in[2];
    const float* s_cop   = (const float*)d_in[3];
    const float* s_grd   = (const float*)d_in[4];
    const float* s_ep    = (const float*)d_in[5];
    const float* s_split = (const float*)d_in[6];
    const float* s_hb    = (const float*)d_in[7];
    const float* s_he    = (const float*)d_in[8];
    const void*  em      = d_in[9];
    (void)in_sizes; (void)n_in; (void)out_size; (void)ws_size;

    float* q_edge = (float*)d_out;
    float* q_span = q_edge + (size_t)BB * S2;

    char* ws = (char*)d_ws;
    const size_t SZ = (size_t)BB * S2 * sizeof(float);   // 256 KiB
    float* split0 = (float*)(ws);
    float* split1 = (float*)(ws + 1*SZ);
    float* peA    = (float*)(ws + 2*SZ);
    float* peTA   = (float*)(ws + 3*SZ);
    float* psA    = (float*)(ws + 4*SZ);
    float* peB    = (float*)(ws + 5*SZ);
    float* peTB   = (float*)(ws + 6*SZ);
    float* psB    = (float*)(ws + 7*SZ);

    const int NB = BB * SDIM;  // 512
    hipLaunchKernelGGL(k_prep, dim3(NB, 2), dim3(256), 0, stream,
                       s_edge, s_const, s_split, em, q_edge, q_span,
                       split0, split1, peA, peB, peTA, peTB, psA, psB);
    for (int it = 0; it < 3; ++it) {
        const int s = it & 1;
        const float* peR  = s ? peB  : peA;
        const float* peTR = s ? peTB : peTA;
        const float* psR  = s ? psB  : psA;
        float* peW  = s ? peA  : peB;
        float* peTW = s ? peTA : peTB;
        float* psW  = s ? psA  : psB;
        hipLaunchKernelGGL(k_upd, dim3(dim3(NB, 8)), dim3(256), 0, stream,
                           s_sib, s_cop, s_grd, s_ep, s_hb, s_he,
                           peR, peTR, psR, split0, split1, em,
                           q_edge, q_span, peW, peTW, psW);
    }
}